// Round 4
// baseline (195.312 us; speedup 1.0000x reference)
//
#include <hip/hip_runtime.h>

#define NBATCH 32
#define NH 16
#define NT 16
#define DD 64
#define SS 1024
#define LL 1024
#define TOTK 2064
#define EE 1024
#define NWAVE 8

typedef __attribute__((ext_vector_type(8))) short bf16x8;
typedef __attribute__((ext_vector_type(4))) float f32x4;

__device__ __forceinline__ unsigned short f2bf(float x) {
  union { float f; unsigned u; } v; v.f = x;
  unsigned r = v.u + 0x7fffu + ((v.u >> 16) & 1u);
  return (unsigned short)(r >> 16);
}

// ---------------- QKV projection ----------------
// grid (8 mtiles, 48 ntiles), 256 threads (4 waves). 64x64 tile, BK=64,
// register-prefetch double buffering.
__global__ __launch_bounds__(256)
void proj_kernel(const float* __restrict__ hidden,
                 const float* __restrict__ Wq, const float* __restrict__ bq,
                 const float* __restrict__ Wk, const float* __restrict__ bk,
                 const float* __restrict__ Wv, const float* __restrict__ bv,
                 unsigned short* __restrict__ qws,
                 float* __restrict__ kws, float* __restrict__ vws)
{
  __shared__ alignas(16) unsigned short As[64][72];
  __shared__ alignas(16) unsigned short Bs[64][72];
  const int mtile = blockIdx.x;
  const int ntile = blockIdx.y;
  const int mat = ntile >> 4;
  const int h = ntile & 15;
  const float* Wm = (mat == 0) ? Wq : (mat == 1 ? Wk : Wv);
  const float* bm = (mat == 0) ? bq : (mat == 1 ? bk : bv);
  const int tid = threadIdx.x;
  const int lane = tid & 63, w = tid >> 6;
  const int lr = lane & 15, lg = lane >> 4;
  const int m0 = mtile * 64;

  const f32x4 fz = {0.f, 0.f, 0.f, 0.f};
  f32x4 acc[4];
  #pragma unroll
  for (int j = 0; j < 4; ++j) acc[j] = fz;

  const int srow = tid >> 4, sc4 = tid & 15;
  float4 Ar[4], Br[4];
  #pragma unroll
  for (int it = 0; it < 4; ++it) {
    Ar[it] = *(const float4*)(hidden + (m0 + srow + it * 16) * EE + sc4 * 4);
    Br[it] = *(const float4*)(Wm + (h * 64 + srow + it * 16) * EE + sc4 * 4);
  }

  for (int k0 = 0; k0 < EE; k0 += 64) {
    __syncthreads();
    #pragma unroll
    for (int it = 0; it < 4; ++it) {
      int row = srow + it * 16;
      float4 a = Ar[it], b = Br[it];
      *(ushort4*)(&As[row][sc4 * 4]) = make_ushort4(f2bf(a.x), f2bf(a.y), f2bf(a.z), f2bf(a.w));
      *(ushort4*)(&Bs[row][sc4 * 4]) = make_ushort4(f2bf(b.x), f2bf(b.y), f2bf(b.z), f2bf(b.w));
    }
    __syncthreads();
    int kn = k0 + 64;
    if (kn < EE) {
      #pragma unroll
      for (int it = 0; it < 4; ++it) {
        Ar[it] = *(const float4*)(hidden + (m0 + srow + it * 16) * EE + kn + sc4 * 4);
        Br[it] = *(const float4*)(Wm + (h * 64 + srow + it * 16) * EE + kn + sc4 * 4);
      }
    }
    #pragma unroll
    for (int hh = 0; hh < 2; ++hh) {
      bf16x8 a = *(const bf16x8*)(&As[w * 16 + lr][hh * 32 + lg * 8]);
      #pragma unroll
      for (int dt = 0; dt < 4; ++dt) {
        bf16x8 b = *(const bf16x8*)(&Bs[dt * 16 + lr][hh * 32 + lg * 8]);
        acc[dt] = __builtin_amdgcn_mfma_f32_16x16x32_bf16(a, b, acc[dt], 0, 0, 0);
      }
    }
  }

  #pragma unroll
  for (int dt = 0; dt < 4; ++dt)
    #pragma unroll
    for (int r = 0; r < 4; ++r) {
      int Mrow = m0 + w * 16 + lg * 4 + r;
      int nb = Mrow >> 4, t = Mrow & 15;
      int d = dt * 16 + lr;
      float val = acc[dt][r] + bm[h * 64 + d];
      int oi = ((nb * NH + h) * NT + t) * DD + d;
      if (mat == 0) qws[oi] = f2bf(val);
      else if (mat == 1) kws[oi] = val;
      else vws[oi] = val;
    }
}

// ---------------- fused prefix attention: 1 block per (nb,h), 8 waves ----------------
__device__ __forceinline__ void tile_src(int tt, int nb, int n, int h,
                                         const float* ppk, const float* ppv,
                                         const float* pk, const float* pv,
                                         const float* kws, const float* vws,
                                         const float*& ksrc, const float*& vsrc,
                                         int& jabs0, int& valid)
{
  if (tt < 32) {
    int j = tt * 32;
    ksrc = ppk + ((n * NH + h) * SS + j) * DD;
    vsrc = ppv + ((n * NH + h) * SS + j) * DD;
    jabs0 = j; valid = 32;
  } else if (tt < 64) {
    int j = (tt - 32) * 32;
    ksrc = pk + ((nb * NH + h) * LL + j) * DD;
    vsrc = pv + ((nb * NH + h) * LL + j) * DD;
    jabs0 = SS + j; valid = 32;
  } else {
    ksrc = kws + ((nb * NH + h) * NT) * DD;
    vsrc = vws + ((nb * NH + h) * NT) * DD;
    jabs0 = SS + LL; valid = 16;
  }
}

__global__ __launch_bounds__(512, 4)
void attn_kernel(const float* __restrict__ mask, const float* __restrict__ rel,
                 const float* __restrict__ ppk, const float* __restrict__ ppv,
                 const float* __restrict__ pk, const float* __restrict__ pv,
                 const unsigned short* __restrict__ qws,
                 const float* __restrict__ kws, const float* __restrict__ vws,
                 float* __restrict__ out)
{
  __shared__ alignas(16) unsigned short Pb[NWAVE][16][40];
  __shared__ float mgc[NWAVE][16][64];
  __shared__ float mgml[NWAVE][16][2];

  const int wg = blockIdx.x;          // 512 = nb*16 + h
  const int nb = wg >> 4, h = wg & 15;
  const int n = nb >> 2;
  const int tid = threadIdx.x;
  const int lane = tid & 63, w = tid >> 6;   // w in 0..7
  const int lr = lane & 15, lg = lane >> 4;

  const unsigned short* qbase = qws + ((nb * NH + h) * NT) * DD;
  bf16x8 aq0 = *(const bf16x8*)(qbase + lr * DD + lg * 8);
  bf16x8 aq1 = *(const bf16x8*)(qbase + lr * DD + lg * 8 + 32);

  const float* relbase = rel + ((nb * NH + h) * NT) * TOTK;
  const float* mbase = mask + nb * TOTK;

  float m_r[4], l_r[4];
  const f32x4 fz = {0.f, 0.f, 0.f, 0.f};
  f32x4 ctx[4];
  #pragma unroll
  for (int r = 0; r < 4; ++r) { m_r[r] = -1e30f; l_r[r] = 0.f; }
  #pragma unroll
  for (int dt = 0; dt < 4; ++dt) ctx[dt] = fz;

  // 65 tiles of 32 keys; wave w owns tt = w, w+8, ...
  for (int tt = w; tt < 65; tt += NWAVE) {
    const float *ksrc, *vsrc; int jabs0, valid;
    tile_src(tt, nb, n, h, ppk, ppv, pk, pv, kws, vws, ksrc, vsrc, jabs0, valid);

    // ---- issue ALL tile loads up front ----
    const float4 z4 = {0.f, 0.f, 0.f, 0.f};
    float4 kraw[8];
    #pragma unroll
    for (int sub = 0; sub < 2; ++sub) {
      int row = sub * 16 + lr;
      bool ok = row < valid;
      #pragma unroll
      for (int hh = 0; hh < 2; ++hh)
        #pragma unroll
        for (int q = 0; q < 2; ++q)
          kraw[(sub * 2 + hh) * 2 + q] =
              ok ? *(const float4*)(ksrc + row * DD + hh * 32 + lg * 8 + q * 4) : z4;
    }
    float vraw[32];
    #pragma unroll
    for (int dt = 0; dt < 4; ++dt)
      #pragma unroll
      for (int e = 0; e < 8; ++e) {
        int j = lg * 8 + e;
        vraw[dt * 8 + e] = (j < valid) ? vsrc[j * DD + dt * 16 + lr] : 0.f;
      }
    float rraw[8];
    #pragma unroll
    for (int sub = 0; sub < 2; ++sub)
      #pragma unroll
      for (int r = 0; r < 4; ++r) {
        int jloc = sub * 16 + lr;
        int t = lg * 4 + r;
        rraw[sub * 4 + r] = (jloc < valid) ? relbase[t * TOTK + jabs0 + jloc] : 0.f;
      }
    float mv[2];
    #pragma unroll
    for (int sub = 0; sub < 2; ++sub) {
      int jloc = sub * 16 + lr;
      mv[sub] = (jloc < valid) ? mbase[jabs0 + jloc] : 0.f;
    }

    // ---- convert K, QK^T ----
    bf16x8 kb[4];
    #pragma unroll
    for (int f = 0; f < 4; ++f) {
      bf16x8 o;
      #pragma unroll
      for (int q = 0; q < 2; ++q) {
        float4 v = kraw[f * 2 + q];
        o[q * 4 + 0] = (short)f2bf(v.x); o[q * 4 + 1] = (short)f2bf(v.y);
        o[q * 4 + 2] = (short)f2bf(v.z); o[q * 4 + 3] = (short)f2bf(v.w);
      }
      kb[f] = o;
    }
    float sc[2][4];
    #pragma unroll
    for (int sub = 0; sub < 2; ++sub) {
      f32x4 s = fz;
      s = __builtin_amdgcn_mfma_f32_16x16x32_bf16(aq0, kb[sub * 2 + 0], s, 0, 0, 0);
      s = __builtin_amdgcn_mfma_f32_16x16x32_bf16(aq1, kb[sub * 2 + 1], s, 0, 0, 0);
      bool jok = (sub * 16 + lr) < valid;
      #pragma unroll
      for (int r = 0; r < 4; ++r)
        sc[sub][r] = jok ? (s[r] * 0.125f + rraw[sub * 4 + r] + mv[sub]) : -1e30f;
    }

    // ---- online softmax ----
    #pragma unroll
    for (int r = 0; r < 4; ++r) {
      float tmax = fmaxf(sc[0][r], sc[1][r]);
      #pragma unroll
      for (int o = 8; o >= 1; o >>= 1) tmax = fmaxf(tmax, __shfl_xor(tmax, o, 16));
      float mnew = fmaxf(m_r[r], tmax);
      float alpha = __expf(m_r[r] - mnew);
      float p0 = __expf(sc[0][r] - mnew);
      float p1 = __expf(sc[1][r] - mnew);
      float rs = p0 + p1;
      #pragma unroll
      for (int o = 8; o >= 1; o >>= 1) rs += __shfl_xor(rs, o, 16);
      l_r[r] = l_r[r] * alpha + rs;
      m_r[r] = mnew;
      #pragma unroll
      for (int dt = 0; dt < 4; ++dt) ctx[dt][r] *= alpha;
      int t = lg * 4 + r;
      Pb[w][t][lr] = f2bf(p0);
      Pb[w][t][16 + lr] = f2bf(p1);
    }

    // ---- convert V, PV ----
    bf16x8 pa = *(const bf16x8*)(&Pb[w][lr][lg * 8]);
    #pragma unroll
    for (int dt = 0; dt < 4; ++dt) {
      bf16x8 vb;
      #pragma unroll
      for (int e = 0; e < 8; ++e) vb[e] = (short)f2bf(vraw[dt * 8 + e]);
      ctx[dt] = __builtin_amdgcn_mfma_f32_16x16x32_bf16(pa, vb, ctx[dt], 0, 0, 0);
    }
  }

  // ---- merge all 8 waves in-block, write final output ----
  __syncthreads();
  #pragma unroll
  for (int dt = 0; dt < 4; ++dt)
    #pragma unroll
    for (int r = 0; r < 4; ++r)
      mgc[w][lg * 4 + r][dt * 16 + lr] = ctx[dt][r];
  if (lr == 0) {
    #pragma unroll
    for (int r = 0; r < 4; ++r) {
      mgml[w][lg * 4 + r][0] = m_r[r];
      mgml[w][lg * 4 + r][1] = l_r[r];
    }
  }
  __syncthreads();
  #pragma unroll
  for (int i = 0; i < 2; ++i) {
    int idx = i * 512 + tid;
    int t = idx >> 6, d = idx & 63;
    float M = -1e30f;
    #pragma unroll
    for (int ww = 0; ww < NWAVE; ++ww) M = fmaxf(M, mgml[ww][t][0]);
    float num = 0.f, den = 0.f;
    #pragma unroll
    for (int ww = 0; ww < NWAVE; ++ww) {
      float e = __expf(mgml[ww][t][0] - M);
      den += mgml[ww][t][1] * e;
      num += mgc[ww][t][d] * e;
    }
    out[((nb * NT + t) * NH + h) * DD + d] = num / den;
  }
}

extern "C" void kernel_launch(void* const* d_in, const int* in_sizes, int n_in,
                              void* d_out, int out_size, void* d_ws, size_t ws_size,
                              hipStream_t stream) {
  const float* hidden = (const float*)d_in[0];
  const float* mask   = (const float*)d_in[1];
  const float* rel    = (const float*)d_in[2];
  const float* ppk    = (const float*)d_in[3];
  const float* ppv    = (const float*)d_in[4];
  const float* pk     = (const float*)d_in[5];
  const float* pv     = (const float*)d_in[6];
  const float* Wq     = (const float*)d_in[7];
  const float* bq     = (const float*)d_in[8];
  const float* Wk     = (const float*)d_in[9];
  const float* bk     = (const float*)d_in[10];
  const float* Wv     = (const float*)d_in[11];
  const float* bv     = (const float*)d_in[12];
  float* out = (float*)d_out;

  unsigned short* qws = (unsigned short*)d_ws;                 // 1 MB bf16 Q
  float* kws = (float*)((char*)d_ws + (1u << 20));             // 2 MB fp32 new K
  float* vws = (float*)((char*)d_ws + 3u * (1u << 20));        // 2 MB fp32 new V

  proj_kernel<<<dim3(8, 48), 256, 0, stream>>>(hidden, Wq, bq, Wk, bk, Wv, bv,
                                               qws, kws, vws);
  attn_kernel<<<dim3(512), 512, 0, stream>>>(mask, rel, ppk, ppv, pk, pv,
                                             qws, kws, vws, out);
}

// Round 5
// 146.226 us; speedup vs baseline: 1.3357x; 1.3357x over previous
//
#include <hip/hip_runtime.h>

#define NBATCH 32
#define NH 16
#define NT 16
#define DD 64
#define SS 1024
#define LL 1024
#define TOTK 2064
#define EE 1024
#define NWAVE 8

typedef __attribute__((ext_vector_type(8))) short bf16x8;
typedef __attribute__((ext_vector_type(4))) float f32x4;

__device__ __forceinline__ unsigned short f2bf(float x) {
  union { float f; unsigned u; } v; v.f = x;
  unsigned r = v.u + 0x7fffu + ((v.u >> 16) & 1u);
  return (unsigned short)(r >> 16);
}

// ---------------- QKV projection ----------------
__global__ __launch_bounds__(256)
void proj_kernel(const float* __restrict__ hidden,
                 const float* __restrict__ Wq, const float* __restrict__ bq,
                 const float* __restrict__ Wk, const float* __restrict__ bk,
                 const float* __restrict__ Wv, const float* __restrict__ bv,
                 unsigned short* __restrict__ qws,
                 float* __restrict__ kws, float* __restrict__ vws)
{
  __shared__ alignas(16) unsigned short As[64][72];
  __shared__ alignas(16) unsigned short Bs[64][72];
  const int mtile = blockIdx.x;
  const int ntile = blockIdx.y;
  const int mat = ntile >> 4;
  const int h = ntile & 15;
  const float* Wm = (mat == 0) ? Wq : (mat == 1 ? Wk : Wv);
  const float* bm = (mat == 0) ? bq : (mat == 1 ? bk : bv);
  const int tid = threadIdx.x;
  const int lane = tid & 63, w = tid >> 6;
  const int lr = lane & 15, lg = lane >> 4;
  const int m0 = mtile * 64;

  const f32x4 fz = {0.f, 0.f, 0.f, 0.f};
  f32x4 acc[4];
  #pragma unroll
  for (int j = 0; j < 4; ++j) acc[j] = fz;

  const int srow = tid >> 4, sc4 = tid & 15;
  float4 Ar[4], Br[4];
  #pragma unroll
  for (int it = 0; it < 4; ++it) {
    Ar[it] = *(const float4*)(hidden + (m0 + srow + it * 16) * EE + sc4 * 4);
    Br[it] = *(const float4*)(Wm + (h * 64 + srow + it * 16) * EE + sc4 * 4);
  }

  for (int k0 = 0; k0 < EE; k0 += 64) {
    __syncthreads();
    #pragma unroll
    for (int it = 0; it < 4; ++it) {
      int row = srow + it * 16;
      float4 a = Ar[it], b = Br[it];
      *(ushort4*)(&As[row][sc4 * 4]) = make_ushort4(f2bf(a.x), f2bf(a.y), f2bf(a.z), f2bf(a.w));
      *(ushort4*)(&Bs[row][sc4 * 4]) = make_ushort4(f2bf(b.x), f2bf(b.y), f2bf(b.z), f2bf(b.w));
    }
    __syncthreads();
    int kn = k0 + 64;
    if (kn < EE) {
      #pragma unroll
      for (int it = 0; it < 4; ++it) {
        Ar[it] = *(const float4*)(hidden + (m0 + srow + it * 16) * EE + kn + sc4 * 4);
        Br[it] = *(const float4*)(Wm + (h * 64 + srow + it * 16) * EE + kn + sc4 * 4);
      }
    }
    #pragma unroll
    for (int hh = 0; hh < 2; ++hh) {
      bf16x8 a = *(const bf16x8*)(&As[w * 16 + lr][hh * 32 + lg * 8]);
      #pragma unroll
      for (int dt = 0; dt < 4; ++dt) {
        bf16x8 b = *(const bf16x8*)(&Bs[dt * 16 + lr][hh * 32 + lg * 8]);
        acc[dt] = __builtin_amdgcn_mfma_f32_16x16x32_bf16(a, b, acc[dt], 0, 0, 0);
      }
    }
  }

  #pragma unroll
  for (int dt = 0; dt < 4; ++dt)
    #pragma unroll
    for (int r = 0; r < 4; ++r) {
      int Mrow = m0 + w * 16 + lg * 4 + r;
      int nb = Mrow >> 4, t = Mrow & 15;
      int d = dt * 16 + lr;
      float val = acc[dt][r] + bm[h * 64 + d];
      int oi = ((nb * NH + h) * NT + t) * DD + d;
      if (mat == 0) qws[oi] = f2bf(val);
      else if (mat == 1) kws[oi] = val;
      else vws[oi] = val;
    }
}

// ---------------- fused prefix attention: 1 block per (nb,h), 8 waves ----------------
__device__ __forceinline__ void tile_src(int tt, int nb, int n, int h,
                                         const float* ppk, const float* ppv,
                                         const float* pk, const float* pv,
                                         const float* kws, const float* vws,
                                         const float*& ksrc, const float*& vsrc,
                                         int& jabs0, int& valid)
{
  if (tt < 32) {
    int j = tt * 32;
    ksrc = ppk + ((n * NH + h) * SS + j) * DD;
    vsrc = ppv + ((n * NH + h) * SS + j) * DD;
    jabs0 = j; valid = 32;
  } else if (tt < 64) {
    int j = (tt - 32) * 32;
    ksrc = pk + ((nb * NH + h) * LL + j) * DD;
    vsrc = pv + ((nb * NH + h) * LL + j) * DD;
    jabs0 = SS + j; valid = 32;
  } else {
    ksrc = kws + ((nb * NH + h) * NT) * DD;
    vsrc = vws + ((nb * NH + h) * NT) * DD;
    jabs0 = SS + LL; valid = 16;
  }
}

__global__ __launch_bounds__(512, 2)
void attn_kernel(const float* __restrict__ mask, const float* __restrict__ rel,
                 const float* __restrict__ ppk, const float* __restrict__ ppv,
                 const float* __restrict__ pk, const float* __restrict__ pv,
                 const unsigned short* __restrict__ qws,
                 const float* __restrict__ kws, const float* __restrict__ vws,
                 float* __restrict__ out)
{
  __shared__ alignas(16) unsigned short Pb[NWAVE][16][40];
  __shared__ float mgc[NWAVE][16][64];
  __shared__ float mgml[NWAVE][16][2];

  const int wg = blockIdx.x;          // 512 = nb*16 + h
  const int nb = wg >> 4, h = wg & 15;
  const int n = nb >> 2;
  const int tid = threadIdx.x;
  const int lane = tid & 63, w = tid >> 6;   // w in 0..7
  const int lr = lane & 15, lg = lane >> 4;

  const unsigned short* qbase = qws + ((nb * NH + h) * NT) * DD;
  bf16x8 aq0 = *(const bf16x8*)(qbase + lr * DD + lg * 8);
  bf16x8 aq1 = *(const bf16x8*)(qbase + lr * DD + lg * 8 + 32);

  const float* relbase = rel + ((nb * NH + h) * NT) * TOTK;
  const float* mbase = mask + nb * TOTK;

  float m_r[4], l_r[4];
  const f32x4 fz = {0.f, 0.f, 0.f, 0.f};
  f32x4 ctx[4];
  #pragma unroll
  for (int r = 0; r < 4; ++r) { m_r[r] = -1e30f; l_r[r] = 0.f; }
  #pragma unroll
  for (int dt = 0; dt < 4; ++dt) ctx[dt] = fz;

  // 65 tiles of 32 keys; wave w owns tt = w, w+8, ...
  for (int tt = w; tt < 65; tt += NWAVE) {
    const float *ksrc, *vsrc; int jabs0, valid;
    tile_src(tt, nb, n, h, ppk, ppv, pk, pv, kws, vws, ksrc, vsrc, jabs0, valid);

    // ---- issue ALL tile loads up front ----
    const float4 z4 = {0.f, 0.f, 0.f, 0.f};
    float4 kraw[8];
    #pragma unroll
    for (int sub = 0; sub < 2; ++sub) {
      int row = sub * 16 + lr;
      bool ok = row < valid;
      #pragma unroll
      for (int hh = 0; hh < 2; ++hh)
        #pragma unroll
        for (int q = 0; q < 2; ++q)
          kraw[(sub * 2 + hh) * 2 + q] =
              ok ? *(const float4*)(ksrc + row * DD + hh * 32 + lg * 8 + q * 4) : z4;
    }
    float vraw[32];
    #pragma unroll
    for (int dt = 0; dt < 4; ++dt)
      #pragma unroll
      for (int e = 0; e < 8; ++e) {
        int j = lg * 8 + e;
        vraw[dt * 8 + e] = (j < valid) ? vsrc[j * DD + dt * 16 + lr] : 0.f;
      }
    float rraw[8];
    #pragma unroll
    for (int sub = 0; sub < 2; ++sub)
      #pragma unroll
      for (int r = 0; r < 4; ++r) {
        int jloc = sub * 16 + lr;
        int t = lg * 4 + r;
        rraw[sub * 4 + r] = (jloc < valid) ? relbase[t * TOTK + jabs0 + jloc] : 0.f;
      }
    float mv[2];
    #pragma unroll
    for (int sub = 0; sub < 2; ++sub) {
      int jloc = sub * 16 + lr;
      mv[sub] = (jloc < valid) ? mbase[jabs0 + jloc] : 0.f;
    }

    // ---- convert K, QK^T ----
    bf16x8 kb[4];
    #pragma unroll
    for (int f = 0; f < 4; ++f) {
      bf16x8 o;
      #pragma unroll
      for (int q = 0; q < 2; ++q) {
        float4 v = kraw[f * 2 + q];
        o[q * 4 + 0] = (short)f2bf(v.x); o[q * 4 + 1] = (short)f2bf(v.y);
        o[q * 4 + 2] = (short)f2bf(v.z); o[q * 4 + 3] = (short)f2bf(v.w);
      }
      kb[f] = o;
    }
    float sc[2][4];
    #pragma unroll
    for (int sub = 0; sub < 2; ++sub) {
      f32x4 s = fz;
      s = __builtin_amdgcn_mfma_f32_16x16x32_bf16(aq0, kb[sub * 2 + 0], s, 0, 0, 0);
      s = __builtin_amdgcn_mfma_f32_16x16x32_bf16(aq1, kb[sub * 2 + 1], s, 0, 0, 0);
      bool jok = (sub * 16 + lr) < valid;
      #pragma unroll
      for (int r = 0; r < 4; ++r)
        sc[sub][r] = jok ? (s[r] * 0.125f + rraw[sub * 4 + r] + mv[sub]) : -1e30f;
    }

    // ---- online softmax ----
    #pragma unroll
    for (int r = 0; r < 4; ++r) {
      float tmax = fmaxf(sc[0][r], sc[1][r]);
      #pragma unroll
      for (int o = 8; o >= 1; o >>= 1) tmax = fmaxf(tmax, __shfl_xor(tmax, o, 16));
      float mnew = fmaxf(m_r[r], tmax);
      float alpha = __expf(m_r[r] - mnew);
      float p0 = __expf(sc[0][r] - mnew);
      float p1 = __expf(sc[1][r] - mnew);
      float rs = p0 + p1;
      #pragma unroll
      for (int o = 8; o >= 1; o >>= 1) rs += __shfl_xor(rs, o, 16);
      l_r[r] = l_r[r] * alpha + rs;
      m_r[r] = mnew;
      #pragma unroll
      for (int dt = 0; dt < 4; ++dt) ctx[dt][r] *= alpha;
      int t = lg * 4 + r;
      Pb[w][t][lr] = f2bf(p0);
      Pb[w][t][16 + lr] = f2bf(p1);
    }

    // ---- convert V, PV ----
    bf16x8 pa = *(const bf16x8*)(&Pb[w][lr][lg * 8]);
    #pragma unroll
    for (int dt = 0; dt < 4; ++dt) {
      bf16x8 vb;
      #pragma unroll
      for (int e = 0; e < 8; ++e) vb[e] = (short)f2bf(vraw[dt * 8 + e]);
      ctx[dt] = __builtin_amdgcn_mfma_f32_16x16x32_bf16(pa, vb, ctx[dt], 0, 0, 0);
    }
  }

  // ---- merge all 8 waves in-block, write final output ----
  __syncthreads();
  #pragma unroll
  for (int dt = 0; dt < 4; ++dt)
    #pragma unroll
    for (int r = 0; r < 4; ++r)
      mgc[w][lg * 4 + r][dt * 16 + lr] = ctx[dt][r];
  if (lr == 0) {
    #pragma unroll
    for (int r = 0; r < 4; ++r) {
      mgml[w][lg * 4 + r][0] = m_r[r];
      mgml[w][lg * 4 + r][1] = l_r[r];
    }
  }
  __syncthreads();
  #pragma unroll
  for (int i = 0; i < 2; ++i) {
    int idx = i * 512 + tid;
    int t = idx >> 6, d = idx & 63;
    float M = -1e30f;
    #pragma unroll
    for (int ww = 0; ww < NWAVE; ++ww) M = fmaxf(M, mgml[ww][t][0]);
    float num = 0.f, den = 0.f;
    #pragma unroll
    for (int ww = 0; ww < NWAVE; ++ww) {
      float e = __expf(mgml[ww][t][0] - M);
      den += mgml[ww][t][1] * e;
      num += mgc[ww][t][d] * e;
    }
    out[((nb * NT + t) * NH + h) * DD + d] = num / den;
  }
}

extern "C" void kernel_launch(void* const* d_in, const int* in_sizes, int n_in,
                              void* d_out, int out_size, void* d_ws, size_t ws_size,
                              hipStream_t stream) {
  const float* hidden = (const float*)d_in[0];
  const float* mask   = (const float*)d_in[1];
  const float* rel    = (const float*)d_in[2];
  const float* ppk    = (const float*)d_in[3];
  const float* ppv    = (const float*)d_in[4];
  const float* pk     = (const float*)d_in[5];
  const float* pv     = (const float*)d_in[6];
  const float* Wq     = (const float*)d_in[7];
  const float* bq     = (const float*)d_in[8];
  const float* Wk     = (const float*)d_in[9];
  const float* bk     = (const float*)d_in[10];
  const float* Wv     = (const float*)d_in[11];
  const float* bv     = (const float*)d_in[12];
  float* out = (float*)d_out;

  unsigned short* qws = (unsigned short*)d_ws;                 // 1 MB bf16 Q
  float* kws = (float*)((char*)d_ws + (1u << 20));             // 2 MB fp32 new K
  float* vws = (float*)((char*)d_ws + 3u * (1u << 20));        // 2 MB fp32 new V

  proj_kernel<<<dim3(8, 48), 256, 0, stream>>>(hidden, Wq, bq, Wk, bk, Wv, bv,
                                               qws, kws, vws);
  attn_kernel<<<dim3(512), 512, 0, stream>>>(mask, rel, ppk, ppv, pk, pv,
                                             qws, kws, vws, out);
}

// Round 6
// 134.467 us; speedup vs baseline: 1.4525x; 1.0874x over previous
//
#include <hip/hip_runtime.h>

#define NBATCH 32
#define NH 16
#define NT 16
#define DD 64
#define SS 1024
#define LL 1024
#define TOTK 2064
#define EE 1024
#define NWAVE 8

typedef __attribute__((ext_vector_type(8))) short bf16x8;
typedef __attribute__((ext_vector_type(4))) float f32x4;

__device__ __forceinline__ unsigned short f2bf(float x) {
  union { float f; unsigned u; } v; v.f = x;
  unsigned r = v.u + 0x7fffu + ((v.u >> 16) & 1u);
  return (unsigned short)(r >> 16);
}

// ---------------- QKV projection (unchanged, validated) ----------------
__global__ __launch_bounds__(256)
void proj_kernel(const float* __restrict__ hidden,
                 const float* __restrict__ Wq, const float* __restrict__ bq,
                 const float* __restrict__ Wk, const float* __restrict__ bk,
                 const float* __restrict__ Wv, const float* __restrict__ bv,
                 unsigned short* __restrict__ qws,
                 float* __restrict__ kws, float* __restrict__ vws)
{
  __shared__ alignas(16) unsigned short As[64][72];
  __shared__ alignas(16) unsigned short Bs[64][72];
  const int mtile = blockIdx.x;
  const int ntile = blockIdx.y;
  const int mat = ntile >> 4;
  const int h = ntile & 15;
  const float* Wm = (mat == 0) ? Wq : (mat == 1 ? Wk : Wv);
  const float* bm = (mat == 0) ? bq : (mat == 1 ? bk : bv);
  const int tid = threadIdx.x;
  const int lane = tid & 63, w = tid >> 6;
  const int lr = lane & 15, lg = lane >> 4;
  const int m0 = mtile * 64;

  const f32x4 fz = {0.f, 0.f, 0.f, 0.f};
  f32x4 acc[4];
  #pragma unroll
  for (int j = 0; j < 4; ++j) acc[j] = fz;

  const int srow = tid >> 4, sc4 = tid & 15;
  float4 Ar[4], Br[4];
  #pragma unroll
  for (int it = 0; it < 4; ++it) {
    Ar[it] = *(const float4*)(hidden + (m0 + srow + it * 16) * EE + sc4 * 4);
    Br[it] = *(const float4*)(Wm + (h * 64 + srow + it * 16) * EE + sc4 * 4);
  }

  for (int k0 = 0; k0 < EE; k0 += 64) {
    __syncthreads();
    #pragma unroll
    for (int it = 0; it < 4; ++it) {
      int row = srow + it * 16;
      float4 a = Ar[it], b = Br[it];
      *(ushort4*)(&As[row][sc4 * 4]) = make_ushort4(f2bf(a.x), f2bf(a.y), f2bf(a.z), f2bf(a.w));
      *(ushort4*)(&Bs[row][sc4 * 4]) = make_ushort4(f2bf(b.x), f2bf(b.y), f2bf(b.z), f2bf(b.w));
    }
    __syncthreads();
    int kn = k0 + 64;
    if (kn < EE) {
      #pragma unroll
      for (int it = 0; it < 4; ++it) {
        Ar[it] = *(const float4*)(hidden + (m0 + srow + it * 16) * EE + kn + sc4 * 4);
        Br[it] = *(const float4*)(Wm + (h * 64 + srow + it * 16) * EE + kn + sc4 * 4);
      }
    }
    #pragma unroll
    for (int hh = 0; hh < 2; ++hh) {
      bf16x8 a = *(const bf16x8*)(&As[w * 16 + lr][hh * 32 + lg * 8]);
      #pragma unroll
      for (int dt = 0; dt < 4; ++dt) {
        bf16x8 b = *(const bf16x8*)(&Bs[dt * 16 + lr][hh * 32 + lg * 8]);
        acc[dt] = __builtin_amdgcn_mfma_f32_16x16x32_bf16(a, b, acc[dt], 0, 0, 0);
      }
    }
  }

  #pragma unroll
  for (int dt = 0; dt < 4; ++dt)
    #pragma unroll
    for (int r = 0; r < 4; ++r) {
      int Mrow = m0 + w * 16 + lg * 4 + r;
      int nb = Mrow >> 4, t = Mrow & 15;
      int d = dt * 16 + lr;
      float val = acc[dt][r] + bm[h * 64 + d];
      int oi = ((nb * NH + h) * NT + t) * DD + d;
      if (mat == 0) qws[oi] = f2bf(val);
      else if (mat == 1) kws[oi] = val;
      else vws[oi] = val;
    }
}

// ---------------- fused prefix attention: no-max softmax + cross-tile pipeline ----------------
__device__ __forceinline__ void tile_src(int tt, int nb, int n, int h,
                                         const float* ppk, const float* ppv,
                                         const float* pk, const float* pv,
                                         const float* kws, const float* vws,
                                         const float*& ksrc, const float*& vsrc,
                                         int& jabs0, int& valid)
{
  if (tt < 32) {
    int j = tt * 32;
    ksrc = ppk + ((n * NH + h) * SS + j) * DD;
    vsrc = ppv + ((n * NH + h) * SS + j) * DD;
    jabs0 = j; valid = 32;
  } else if (tt < 64) {
    int j = (tt - 32) * 32;
    ksrc = pk + ((nb * NH + h) * LL + j) * DD;
    vsrc = pv + ((nb * NH + h) * LL + j) * DD;
    jabs0 = SS + j; valid = 32;
  } else {
    ksrc = kws + ((nb * NH + h) * NT) * DD;
    vsrc = vws + ((nb * NH + h) * NT) * DD;
    jabs0 = SS + LL; valid = 16;
  }
}

__global__ __launch_bounds__(512, 2)
void attn_kernel(const float* __restrict__ mask, const float* __restrict__ rel,
                 const float* __restrict__ ppk, const float* __restrict__ ppv,
                 const float* __restrict__ pk, const float* __restrict__ pv,
                 const unsigned short* __restrict__ qws,
                 const float* __restrict__ kws, const float* __restrict__ vws,
                 float* __restrict__ out)
{
  __shared__ alignas(16) unsigned short Pb[NWAVE][16][40];
  __shared__ float mgc[NWAVE][16][64];
  __shared__ float mgl[NWAVE][16];

  const int wg = blockIdx.x;          // 512 = nb*16 + h
  const int nb = wg >> 4, h = wg & 15;
  const int n = nb >> 2;
  const int tid = threadIdx.x;
  const int lane = tid & 63, w = tid >> 6;   // w in 0..7
  const int lr = lane & 15, lg = lane >> 4;

  const unsigned short* qbase = qws + ((nb * NH + h) * NT) * DD;
  bf16x8 aq0 = *(const bf16x8*)(qbase + lr * DD + lg * 8);
  bf16x8 aq1 = *(const bf16x8*)(qbase + lr * DD + lg * 8 + 32);

  const float* relbase = rel + ((nb * NH + h) * NT) * TOTK;
  const float* mbase = mask + nb * TOTK;

  const f32x4 fz = {0.f, 0.f, 0.f, 0.f};
  f32x4 ctx[4];
  float ls[4];
  #pragma unroll
  for (int dt = 0; dt < 4; ++dt) ctx[dt] = fz;
  #pragma unroll
  for (int r = 0; r < 4; ++r) ls[r] = 0.f;

  // raw prefetch buffers (single-buffered; freed by convert before refill)
  float4 kraw[8];
  float vraw[32];
  float rraw[8];
  float mraw[2];

  auto load_raw = [&](int tt, int& jabs0_, int& valid_) {
    const float *ksrc, *vsrc;
    tile_src(tt, nb, n, h, ppk, ppv, pk, pv, kws, vws, ksrc, vsrc, jabs0_, valid_);
    const float4 z4 = {0.f, 0.f, 0.f, 0.f};
    #pragma unroll
    for (int sub = 0; sub < 2; ++sub) {
      int row = sub * 16 + lr;
      bool ok = row < valid_;
      #pragma unroll
      for (int hh = 0; hh < 2; ++hh)
        #pragma unroll
        for (int q = 0; q < 2; ++q)
          kraw[(sub * 2 + hh) * 2 + q] =
              ok ? *(const float4*)(ksrc + row * DD + hh * 32 + lg * 8 + q * 4) : z4;
    }
    #pragma unroll
    for (int dt = 0; dt < 4; ++dt)
      #pragma unroll
      for (int e = 0; e < 8; ++e) {
        int j = lg * 8 + e;
        vraw[dt * 8 + e] = (j < valid_) ? vsrc[j * DD + dt * 16 + lr] : 0.f;
      }
    #pragma unroll
    for (int sub = 0; sub < 2; ++sub)
      #pragma unroll
      for (int r = 0; r < 4; ++r) {
        int jloc = sub * 16 + lr;
        int t = lg * 4 + r;
        rraw[sub * 4 + r] = (jloc < valid_) ? relbase[t * TOTK + jabs0_ + jloc] : 0.f;
      }
    #pragma unroll
    for (int sub = 0; sub < 2; ++sub) {
      int jloc = sub * 16 + lr;
      mraw[sub] = (jloc < valid_) ? mbase[jabs0_ + jloc] : 0.f;
    }
  };

  // prologue: load first tile
  int tt = w, cj, cv;
  load_raw(tt, cj, cv);

  while (true) {
    // ---- convert raws -> bf16 fragments (frees raw buffers) ----
    bf16x8 kb[4];
    #pragma unroll
    for (int f = 0; f < 4; ++f) {
      bf16x8 o;
      #pragma unroll
      for (int q = 0; q < 2; ++q) {
        float4 v = kraw[f * 2 + q];
        o[q * 4 + 0] = (short)f2bf(v.x); o[q * 4 + 1] = (short)f2bf(v.y);
        o[q * 4 + 2] = (short)f2bf(v.z); o[q * 4 + 3] = (short)f2bf(v.w);
      }
      kb[f] = o;
    }
    bf16x8 vb[4];
    #pragma unroll
    for (int dt = 0; dt < 4; ++dt) {
      bf16x8 o;
      #pragma unroll
      for (int e = 0; e < 8; ++e) o[e] = (short)f2bf(vraw[dt * 8 + e]);
      vb[dt] = o;
    }
    float rc[8];
    #pragma unroll
    for (int i = 0; i < 8; ++i) rc[i] = rraw[i];
    float mv[2];
    mv[0] = mraw[0]; mv[1] = mraw[1];

    // ---- issue next tile's loads (in flight under compute below) ----
    int ttn = tt + NWAVE;
    bool hn = ttn < 65;
    int nj = 0, nv = 0;
    if (hn) load_raw(ttn, nj, nv);

    // ---- QK^T ----
    float sc[2][4];
    #pragma unroll
    for (int sub = 0; sub < 2; ++sub) {
      f32x4 s = fz;
      s = __builtin_amdgcn_mfma_f32_16x16x32_bf16(aq0, kb[sub * 2 + 0], s, 0, 0, 0);
      s = __builtin_amdgcn_mfma_f32_16x16x32_bf16(aq1, kb[sub * 2 + 1], s, 0, 0, 0);
      #pragma unroll
      for (int r = 0; r < 4; ++r)
        sc[sub][r] = s[r] * 0.125f + rc[sub * 4 + r] + mv[sub];
    }

    // ---- no-max softmax: p = exp(s), accumulate per-lane partial sum ----
    #pragma unroll
    for (int r = 0; r < 4; ++r) {
      bool ok0 = lr < cv, ok1 = (16 + lr) < cv;
      float p0 = ok0 ? __expf(sc[0][r]) : 0.f;
      float p1 = ok1 ? __expf(sc[1][r]) : 0.f;
      ls[r] += p0 + p1;
      int t = lg * 4 + r;
      Pb[w][t][lr] = f2bf(p0);
      Pb[w][t][16 + lr] = f2bf(p1);
    }

    // ---- PV ----
    bf16x8 pa = *(const bf16x8*)(&Pb[w][lr][lg * 8]);
    #pragma unroll
    for (int dt = 0; dt < 4; ++dt)
      ctx[dt] = __builtin_amdgcn_mfma_f32_16x16x32_bf16(pa, vb[dt], ctx[dt], 0, 0, 0);

    if (!hn) break;
    tt = ttn; cj = nj; cv = nv;
  }

  // ---- final l reduce across the 16 lanes of each group (once per kernel) ----
  #pragma unroll
  for (int r = 0; r < 4; ++r) {
    #pragma unroll
    for (int o = 8; o >= 1; o >>= 1) ls[r] += __shfl_xor(ls[r], o, 16);
  }

  // ---- merge all 8 waves in-block, write final output ----
  __syncthreads();
  #pragma unroll
  for (int dt = 0; dt < 4; ++dt)
    #pragma unroll
    for (int r = 0; r < 4; ++r)
      mgc[w][lg * 4 + r][dt * 16 + lr] = ctx[dt][r];
  if (lr == 0) {
    #pragma unroll
    for (int r = 0; r < 4; ++r) mgl[w][lg * 4 + r] = ls[r];
  }
  __syncthreads();
  #pragma unroll
  for (int i = 0; i < 2; ++i) {
    int idx = i * 512 + tid;
    int t = idx >> 6, d = idx & 63;
    float num = 0.f, den = 0.f;
    #pragma unroll
    for (int ww = 0; ww < NWAVE; ++ww) {
      den += mgl[ww][t];
      num += mgc[ww][t][d];
    }
    out[((nb * NT + t) * NH + h) * DD + d] = num / den;
  }
}

extern "C" void kernel_launch(void* const* d_in, const int* in_sizes, int n_in,
                              void* d_out, int out_size, void* d_ws, size_t ws_size,
                              hipStream_t stream) {
  const float* hidden = (const float*)d_in[0];
  const float* mask   = (const float*)d_in[1];
  const float* rel    = (const float*)d_in[2];
  const float* ppk    = (const float*)d_in[3];
  const float* ppv    = (const float*)d_in[4];
  const float* pk     = (const float*)d_in[5];
  const float* pv     = (const float*)d_in[6];
  const float* Wq     = (const float*)d_in[7];
  const float* bq     = (const float*)d_in[8];
  const float* Wk     = (const float*)d_in[9];
  const float* bk     = (const float*)d_in[10];
  const float* Wv     = (const float*)d_in[11];
  const float* bv     = (const float*)d_in[12];
  float* out = (float*)d_out;

  unsigned short* qws = (unsigned short*)d_ws;                 // 1 MB bf16 Q
  float* kws = (float*)((char*)d_ws + (1u << 20));             // 2 MB fp32 new K
  float* vws = (float*)((char*)d_ws + 3u * (1u << 20));        // 2 MB fp32 new V

  proj_kernel<<<dim3(8, 48), 256, 0, stream>>>(hidden, Wq, bq, Wk, bk, Wv, bv,
                                               qws, kws, vws);
  attn_kernel<<<dim3(512), 512, 0, stream>>>(mask, rel, ppk, ppv, pk, pv,
                                             qws, kws, vws, out);
}

// Round 8
// 116.969 us; speedup vs baseline: 1.6698x; 1.1496x over previous
//
#include <hip/hip_runtime.h>

#define NH 16
#define NT 16
#define DD 64
#define SS 1024
#define LL 1024
#define TOTK 2064
#define EE 1024
#define NWAVE 8

typedef __attribute__((ext_vector_type(8))) short bf16x8;
typedef __attribute__((ext_vector_type(4))) float f32x4;

__device__ __forceinline__ unsigned short f2bf(float x) {
  union { float f; unsigned u; } v; v.f = x;
  unsigned r = v.u + 0x7fffu + ((v.u >> 16) & 1u);
  return (unsigned short)(r >> 16);
}

// async global->LDS DMA, 16B per lane; LDS dest = wave-uniform base + lane*16,
// global src is per-lane (m104/m173 semantics)
__device__ __forceinline__ void dma16(const void* g, void* l) {
  __builtin_amdgcn_global_load_lds(
      (const __attribute__((address_space(1))) unsigned int*)g,
      (__attribute__((address_space(3))) unsigned int*)l, 16, 0, 0);
}

// ---------------- QKV projection (unchanged, validated) ----------------
__global__ __launch_bounds__(256)
void proj_kernel(const float* __restrict__ hidden,
                 const float* __restrict__ Wq, const float* __restrict__ bq,
                 const float* __restrict__ Wk, const float* __restrict__ bk,
                 const float* __restrict__ Wv, const float* __restrict__ bv,
                 unsigned short* __restrict__ qws,
                 float* __restrict__ kws, float* __restrict__ vws)
{
  __shared__ alignas(16) unsigned short As[64][72];
  __shared__ alignas(16) unsigned short Bs[64][72];
  const int mtile = blockIdx.x;
  const int ntile = blockIdx.y;
  const int mat = ntile >> 4;
  const int h = ntile & 15;
  const float* Wm = (mat == 0) ? Wq : (mat == 1 ? Wk : Wv);
  const float* bm = (mat == 0) ? bq : (mat == 1 ? bk : bv);
  const int tid = threadIdx.x;
  const int lane = tid & 63, w = tid >> 6;
  const int lr = lane & 15, lg = lane >> 4;
  const int m0 = mtile * 64;

  const f32x4 fz = {0.f, 0.f, 0.f, 0.f};
  f32x4 acc[4];
  #pragma unroll
  for (int j = 0; j < 4; ++j) acc[j] = fz;

  const int srow = tid >> 4, sc4 = tid & 15;
  float4 Ar[4], Br[4];
  #pragma unroll
  for (int it = 0; it < 4; ++it) {
    Ar[it] = *(const float4*)(hidden + (m0 + srow + it * 16) * EE + sc4 * 4);
    Br[it] = *(const float4*)(Wm + (h * 64 + srow + it * 16) * EE + sc4 * 4);
  }

  for (int k0 = 0; k0 < EE; k0 += 64) {
    __syncthreads();
    #pragma unroll
    for (int it = 0; it < 4; ++it) {
      int row = srow + it * 16;
      float4 a = Ar[it], b = Br[it];
      *(ushort4*)(&As[row][sc4 * 4]) = make_ushort4(f2bf(a.x), f2bf(a.y), f2bf(a.z), f2bf(a.w));
      *(ushort4*)(&Bs[row][sc4 * 4]) = make_ushort4(f2bf(b.x), f2bf(b.y), f2bf(b.z), f2bf(b.w));
    }
    __syncthreads();
    int kn = k0 + 64;
    if (kn < EE) {
      #pragma unroll
      for (int it = 0; it < 4; ++it) {
        Ar[it] = *(const float4*)(hidden + (m0 + srow + it * 16) * EE + kn + sc4 * 4);
        Br[it] = *(const float4*)(Wm + (h * 64 + srow + it * 16) * EE + kn + sc4 * 4);
      }
    }
    #pragma unroll
    for (int hh = 0; hh < 2; ++hh) {
      bf16x8 a = *(const bf16x8*)(&As[w * 16 + lr][hh * 32 + lg * 8]);
      #pragma unroll
      for (int dt = 0; dt < 4; ++dt) {
        bf16x8 b = *(const bf16x8*)(&Bs[dt * 16 + lr][hh * 32 + lg * 8]);
        acc[dt] = __builtin_amdgcn_mfma_f32_16x16x32_bf16(a, b, acc[dt], 0, 0, 0);
      }
    }
  }

  #pragma unroll
  for (int dt = 0; dt < 4; ++dt)
    #pragma unroll
    for (int r = 0; r < 4; ++r) {
      int Mrow = m0 + w * 16 + lg * 4 + r;
      int nb = Mrow >> 4, t = Mrow & 15;
      int d = dt * 16 + lr;
      float val = acc[dt][r] + bm[h * 64 + d];
      int oi = ((nb * NH + h) * NT + t) * DD + d;
      if (mat == 0) qws[oi] = f2bf(val);
      else if (mat == 1) kws[oi] = val;
      else vws[oi] = val;
    }
}

// ---------------- fused prefix attention: DMA-staged, per-wave slices ----------------
// Block = 8 waves = one (nb,h). Chunk = 128 keys (16/wave).
// LDS: 2 x (K 32KB + V 32KB) dbuf + Pb. No intra-loop barriers.
__global__ __launch_bounds__(512)
void attn_kernel(const float* __restrict__ mask, const float* __restrict__ rel,
                 const float* __restrict__ ppk, const float* __restrict__ ppv,
                 const float* __restrict__ pk, const float* __restrict__ pv,
                 const unsigned short* __restrict__ qws,
                 const float* __restrict__ kws, const float* __restrict__ vws,
                 float* __restrict__ out)
{
  __shared__ __align__(16) float SB[2 * 2 * 128 * 64];       // 128 KB
  __shared__ __align__(16) unsigned short Pb[NWAVE][16][40]; // 10 KB

  const int wg = blockIdx.x;          // 512 = nb*16 + h
  const int nb = wg >> 4, h = wg & 15;
  const int n = nb >> 2;
  const int tid = threadIdx.x;
  const int lane = tid & 63, w = tid >> 6;
  const int lr = lane & 15, lg = lane >> 4;

  const unsigned short* qbase = qws + ((nb * NH + h) * NT) * DD;
  bf16x8 aq0 = *(const bf16x8*)(qbase + lr * DD + lg * 8);
  bf16x8 aq1 = *(const bf16x8*)(qbase + lr * DD + lg * 8 + 32);

  const float* relbase = rel + ((nb * NH + h) * NT) * TOTK;
  const float* mbase = mask + nb * TOTK;

  // zero the padded P columns (keys 16..31): shorts 16..31 of every row.
  // Two ALIGNED 16B stores per row at shorts 16 and 24 (bytes 32, 48).
  // (round 7 bug: half*4 left shorts 28..31 as LDS garbage -> NaN in PV)
  if (lane < 32) {
    int t = lane & 15, half = lane >> 4;
    float4 z = {0.f, 0.f, 0.f, 0.f};
    *(float4*)(&Pb[w][t][16 + half * 8]) = z;
  }

  const f32x4 fz = {0.f, 0.f, 0.f, 0.f};
  f32x4 ctx[4];
  float ls[4];
  #pragma unroll
  for (int dt = 0; dt < 4; ++dt) ctx[dt] = fz;
  #pragma unroll
  for (int r = 0; r < 4; ++r) ls[r] = 0.f;

  // chunk c in [0,17): 0-7 prefix, 8-15 past, 16 new(16 keys)
  auto stage = [&](int c, int buf) {
    const float *ks, *vs;
    if (c < 8) {
      int j = c * 128;
      ks = ppk + ((n * NH + h) * SS + j) * DD;
      vs = ppv + ((n * NH + h) * SS + j) * DD;
    } else if (c < 16) {
      int j = (c - 8) * 128;
      ks = pk + ((nb * NH + h) * LL + j) * DD;
      vs = pv + ((nb * NH + h) * LL + j) * DD;
    } else {
      ks = kws + ((nb * NH + h) * NT) * DD;
      vs = vws + ((nb * NH + h) * NT) * DD;
    }
    float* Kb = SB + buf * 2 * 128 * 64;
    float* Vb = Kb + 128 * 64;
    #pragma unroll
    for (int q = 0; q < 4; ++q) {
      int Lrow = w * 16 + q * 4 + (lane >> 4);       // row this lane covers
      int colb = (lane & 15) * 16;                   // byte col in 256B row
      int scolb = colb ^ ((Lrow & 7) << 4);          // inverse swizzle on source
      int srow = (c == 16) ? (Lrow & 15) : Lrow;     // clamp partial chunk
      const char* gk = (const char*)ks + srow * 256 + scolb;
      const char* gv = (const char*)vs + srow * 256 + scolb;
      dma16(gk, Kb + (w * 16 + q * 4) * 64);
      dma16(gv, Vb + (w * 16 + q * 4) * 64);
    }
  };

  stage(0, 0);  // prologue: 8 DMA in flight

  for (int c = 0; c < 17; ++c) {
    const int buf = c & 1;
    const int kb0 = c * 128 + w * 16;   // absolute first key of this wave's slice
    const bool active = kb0 < TOTK;

    // rel/mask register loads BEFORE next stage: one counted vmcnt retires
    // {this chunk's DMA + these loads} while leaving the prefetch in flight
    float rraw[4]; float mv = 0.f;
    if (active) {
      #pragma unroll
      for (int r = 0; r < 4; ++r)
        rraw[r] = relbase[(lg * 4 + r) * TOTK + kb0 + lr];
      mv = mbase[kb0 + lr];
    }

    if (c < 16) stage(c + 1, buf ^ 1);

    __builtin_amdgcn_sched_barrier(0);
    if (c < 16) asm volatile("s_waitcnt vmcnt(8)" ::: "memory");
    else        asm volatile("s_waitcnt vmcnt(0)" ::: "memory");
    __builtin_amdgcn_sched_barrier(0);

    if (active) {
      const float* Kb = SB + buf * 2 * 128 * 64;
      const float* Vb = Kb + 128 * 64;

      // K fragment: swizzled b128 LDS reads
      bf16x8 kbf[2];
      #pragma unroll
      for (int hh = 0; hh < 2; ++hh) {
        bf16x8 o;
        #pragma unroll
        for (int q = 0; q < 2; ++q) {
          int colb = (hh * 128 + lg * 32 + q * 16) ^ ((lr & 7) << 4);
          float4 v = *(const float4*)((const char*)Kb + (w * 16 + lr) * 256 + colb);
          o[q * 4 + 0] = (short)f2bf(v.x); o[q * 4 + 1] = (short)f2bf(v.y);
          o[q * 4 + 2] = (short)f2bf(v.z); o[q * 4 + 3] = (short)f2bf(v.w);
        }
        kbf[hh] = o;
      }
      f32x4 s = fz;
      s = __builtin_amdgcn_mfma_f32_16x16x32_bf16(aq0, kbf[0], s, 0, 0, 0);
      s = __builtin_amdgcn_mfma_f32_16x16x32_bf16(aq1, kbf[1], s, 0, 0, 0);

      // no-max softmax; 16 keys per wave always fully valid (2064 = 129*16)
      #pragma unroll
      for (int r = 0; r < 4; ++r) {
        float p = __expf(s[r] * 0.125f + rraw[r] + mv);
        ls[r] += p;
        Pb[w][lg * 4 + r][lr] = f2bf(p);
      }

      // PV: P padded with zeros for keys 16..31
      bf16x8 pa = *(const bf16x8*)(&Pb[w][lr][lg * 8]);
      #pragma unroll
      for (int dt = 0; dt < 4; ++dt) {
        bf16x8 vb;
        #pragma unroll
        for (int e = 0; e < 8; ++e) {
          int row = lg * 8 + e;
          float vv = 0.f;
          if (row < 16) {
            int colb = ((dt * 16 + lr) * 4) ^ ((row & 7) << 4);
            vv = *(const float*)((const char*)Vb + (w * 16 + row) * 256 + colb);
          }
          vb[e] = (short)f2bf(vv);
        }
        ctx[dt] = __builtin_amdgcn_mfma_f32_16x16x32_bf16(pa, vb, ctx[dt], 0, 0, 0);
      }
    }
  }

  // per-row l reduce across the 16 lanes of each group
  #pragma unroll
  for (int r = 0; r < 4; ++r) {
    #pragma unroll
    for (int o = 8; o >= 1; o >>= 1) ls[r] += __shfl_xor(ls[r], o, 16);
  }

  // merge 8 waves; reuse SB (all DMA retired, barrier below)
  __syncthreads();
  float* mgc = SB;                   // [8][16][64]
  float* mgl = SB + NWAVE * 16 * 64; // [8][16]
  #pragma unroll
  for (int dt = 0; dt < 4; ++dt)
    #pragma unroll
    for (int r = 0; r < 4; ++r)
      mgc[(w * 16 + lg * 4 + r) * 64 + dt * 16 + lr] = ctx[dt][r];
  if (lr == 0) {
    #pragma unroll
    for (int r = 0; r < 4; ++r) mgl[w * 16 + lg * 4 + r] = ls[r];
  }
  __syncthreads();
  #pragma unroll
  for (int i = 0; i < 2; ++i) {
    int idx = i * 512 + tid;
    int t = idx >> 6, d = idx & 63;
    float num = 0.f, den = 0.f;
    #pragma unroll
    for (int ww = 0; ww < NWAVE; ++ww) {
      den += mgl[ww * 16 + t];
      num += mgc[(ww * 16 + t) * 64 + d];
    }
    out[((nb * NT + t) * NH + h) * DD + d] = num / den;
  }
}

extern "C" void kernel_launch(void* const* d_in, const int* in_sizes, int n_in,
                              void* d_out, int out_size, void* d_ws, size_t ws_size,
                              hipStream_t stream) {
  const float* hidden = (const float*)d_in[0];
  const float* mask   = (const float*)d_in[1];
  const float* rel    = (const float*)d_in[2];
  const float* ppk    = (const float*)d_in[3];
  const float* ppv    = (const float*)d_in[4];
  const float* pk     = (const float*)d_in[5];
  const float* pv     = (const float*)d_in[6];
  const float* Wq     = (const float*)d_in[7];
  const float* bq     = (const float*)d_in[8];
  const float* Wk     = (const float*)d_in[9];
  const float* bk     = (const float*)d_in[10];
  const float* Wv     = (const float*)d_in[11];
  const float* bv     = (const float*)d_in[12];
  float* out = (float*)d_out;

  unsigned short* qws = (unsigned short*)d_ws;                 // 1 MB bf16 Q
  float* kws = (float*)((char*)d_ws + (1u << 20));             // 2 MB fp32 new K
  float* vws = (float*)((char*)d_ws + 3u * (1u << 20));        // 2 MB fp32 new V

  proj_kernel<<<dim3(8, 48), 256, 0, stream>>>(hidden, Wq, bq, Wk, bk, Wv, bv,
                                               qws, kws, vws);
  attn_kernel<<<dim3(512), 512, 0, stream>>>(mask, rel, ppk, ppv, pk, pv,
                                             qws, kws, vws, out);
}

// Round 9
// 111.080 us; speedup vs baseline: 1.7583x; 1.0530x over previous
//
#include <hip/hip_runtime.h>

#define NH 16
#define NT 16
#define DD 64
#define SS 1024
#define LL 1024
#define TOTK 2064
#define EE 1024
#define NWAVE 8

typedef __attribute__((ext_vector_type(8))) short bf16x8;
typedef __attribute__((ext_vector_type(4))) float f32x4;

__device__ __forceinline__ unsigned short f2bf(float x) {
  union { float f; unsigned u; } v; v.f = x;
  unsigned r = v.u + 0x7fffu + ((v.u >> 16) & 1u);
  return (unsigned short)(r >> 16);
}

// async global->LDS DMA, 16B/lane; LDS dest = wave-uniform base + lane*16
__device__ __forceinline__ void dma16(const void* g, void* l) {
  __builtin_amdgcn_global_load_lds(
      (const __attribute__((address_space(1))) unsigned int*)g,
      (__attribute__((address_space(3))) unsigned int*)l, 16, 0, 0);
}

// ---------------- QKV projection (unchanged, validated) ----------------
__global__ __launch_bounds__(256)
void proj_kernel(const float* __restrict__ hidden,
                 const float* __restrict__ Wq, const float* __restrict__ bq,
                 const float* __restrict__ Wk, const float* __restrict__ bk,
                 const float* __restrict__ Wv, const float* __restrict__ bv,
                 unsigned short* __restrict__ qws,
                 float* __restrict__ kws, float* __restrict__ vws)
{
  __shared__ alignas(16) unsigned short As[64][72];
  __shared__ alignas(16) unsigned short Bs[64][72];
  const int mtile = blockIdx.x;
  const int ntile = blockIdx.y;
  const int mat = ntile >> 4;
  const int h = ntile & 15;
  const float* Wm = (mat == 0) ? Wq : (mat == 1 ? Wk : Wv);
  const float* bm = (mat == 0) ? bq : (mat == 1 ? bk : bv);
  const int tid = threadIdx.x;
  const int lane = tid & 63, w = tid >> 6;
  const int lr = lane & 15, lg = lane >> 4;
  const int m0 = mtile * 64;

  const f32x4 fz = {0.f, 0.f, 0.f, 0.f};
  f32x4 acc[4];
  #pragma unroll
  for (int j = 0; j < 4; ++j) acc[j] = fz;

  const int srow = tid >> 4, sc4 = tid & 15;
  float4 Ar[4], Br[4];
  #pragma unroll
  for (int it = 0; it < 4; ++it) {
    Ar[it] = *(const float4*)(hidden + (m0 + srow + it * 16) * EE + sc4 * 4);
    Br[it] = *(const float4*)(Wm + (h * 64 + srow + it * 16) * EE + sc4 * 4);
  }

  for (int k0 = 0; k0 < EE; k0 += 64) {
    __syncthreads();
    #pragma unroll
    for (int it = 0; it < 4; ++it) {
      int row = srow + it * 16;
      float4 a = Ar[it], b = Br[it];
      *(ushort4*)(&As[row][sc4 * 4]) = make_ushort4(f2bf(a.x), f2bf(a.y), f2bf(a.z), f2bf(a.w));
      *(ushort4*)(&Bs[row][sc4 * 4]) = make_ushort4(f2bf(b.x), f2bf(b.y), f2bf(b.z), f2bf(b.w));
    }
    __syncthreads();
    int kn = k0 + 64;
    if (kn < EE) {
      #pragma unroll
      for (int it = 0; it < 4; ++it) {
        Ar[it] = *(const float4*)(hidden + (m0 + srow + it * 16) * EE + kn + sc4 * 4);
        Br[it] = *(const float4*)(Wm + (h * 64 + srow + it * 16) * EE + kn + sc4 * 4);
      }
    }
    #pragma unroll
    for (int hh = 0; hh < 2; ++hh) {
      bf16x8 a = *(const bf16x8*)(&As[w * 16 + lr][hh * 32 + lg * 8]);
      #pragma unroll
      for (int dt = 0; dt < 4; ++dt) {
        bf16x8 b = *(const bf16x8*)(&Bs[dt * 16 + lr][hh * 32 + lg * 8]);
        acc[dt] = __builtin_amdgcn_mfma_f32_16x16x32_bf16(a, b, acc[dt], 0, 0, 0);
      }
    }
  }

  #pragma unroll
  for (int dt = 0; dt < 4; ++dt)
    #pragma unroll
    for (int r = 0; r < 4; ++r) {
      int Mrow = m0 + w * 16 + lg * 4 + r;
      int nb = Mrow >> 4, t = Mrow & 15;
      int d = dt * 16 + lr;
      float val = acc[dt][r] + bm[h * 64 + d];
      int oi = ((nb * NH + h) * NT + t) * DD + d;
      if (mat == 0) qws[oi] = f2bf(val);
      else if (mat == 1) kws[oi] = val;
      else vws[oi] = val;
    }
}

// ---------------- fused prefix attention: DMA K, register V, pair PV ----------------
// Block = 8 waves = one (nb,h). Sub-chunk = 128 keys (16/wave); pairs -> 32-key PV.
// LDS: K dbuf 64KB + Pb 10KB = 74KB -> 2 blocks/CU.
__global__ __launch_bounds__(512, 2)
void attn_kernel(const float* __restrict__ mask, const float* __restrict__ rel,
                 const float* __restrict__ ppk, const float* __restrict__ ppv,
                 const float* __restrict__ pk, const float* __restrict__ pv,
                 const unsigned short* __restrict__ qws,
                 const float* __restrict__ kws, const float* __restrict__ vws,
                 float* __restrict__ out)
{
  __shared__ __align__(16) float SB[2 * 128 * 64];           // 64 KB K dbuf
  __shared__ __align__(16) unsigned short Pb[NWAVE][16][40]; // 10 KB

  const int wg = blockIdx.x;          // 512 = nb*16 + h
  const int nb = wg >> 4, h = wg & 15;
  const int n = nb >> 2;
  const int tid = threadIdx.x;
  const int lane = tid & 63, w = tid >> 6;
  const int lr = lane & 15, lg = lane >> 4;

  const unsigned short* qbase = qws + ((nb * NH + h) * NT) * DD;
  bf16x8 aq0 = *(const bf16x8*)(qbase + lr * DD + lg * 8);
  bf16x8 aq1 = *(const bf16x8*)(qbase + lr * DD + lg * 8 + 32);

  const float* relbase = rel + ((nb * NH + h) * NT) * TOTK;
  const float* mbase = mask + nb * TOTK;

  const f32x4 fz = {0.f, 0.f, 0.f, 0.f};
  f32x4 ctx[4];
  float ls[4];
  #pragma unroll
  for (int dt = 0; dt < 4; ++dt) ctx[dt] = fz;
  #pragma unroll
  for (int r = 0; r < 4; ++r) ls[r] = 0.f;

  // stage one 128-key K sub-chunk (this wave's 16 rows), 4 DMA
  auto kstage = [&](int c, int buf) {
    const float* ks = (c < 8)  ? ppk + ((n * NH + h) * SS + c * 128) * DD
                    : (c < 16) ? pk + ((nb * NH + h) * LL + (c - 8) * 128) * DD
                               : kws + ((nb * NH + h) * NT) * DD;
    float* Kb = SB + buf * 128 * 64;
    #pragma unroll
    for (int q = 0; q < 4; ++q) {
      int Lrow = w * 16 + q * 4 + (lane >> 4);
      int colb = (lane & 15) * 16;
      int scolb = colb ^ ((Lrow & 7) << 4);          // inverse swizzle on source
      int srow = (c == 16) ? (Lrow & 15) : Lrow;
      dma16((const char*)ks + srow * 256 + scolb, Kb + (w * 16 + q * 4) * 64);
    }
  };

  // QK^T for one 16-key sub-chunk; writes Pb column block [sub*16 + lr]
  auto qk_sub = [&](const float* Kb, const float rr[4], float mv, int sub) {
    bf16x8 kbf[2];
    #pragma unroll
    for (int hh = 0; hh < 2; ++hh) {
      bf16x8 o;
      #pragma unroll
      for (int q = 0; q < 2; ++q) {
        int colb = (hh * 128 + lg * 32 + q * 16) ^ ((lr & 7) << 4);
        float4 v = *(const float4*)((const char*)Kb + (w * 16 + lr) * 256 + colb);
        o[q * 4 + 0] = (short)f2bf(v.x); o[q * 4 + 1] = (short)f2bf(v.y);
        o[q * 4 + 2] = (short)f2bf(v.z); o[q * 4 + 3] = (short)f2bf(v.w);
      }
      kbf[hh] = o;
    }
    f32x4 s = fz;
    s = __builtin_amdgcn_mfma_f32_16x16x32_bf16(aq0, kbf[0], s, 0, 0, 0);
    s = __builtin_amdgcn_mfma_f32_16x16x32_bf16(aq1, kbf[1], s, 0, 0, 0);
    #pragma unroll
    for (int r = 0; r < 4; ++r) {
      float p = __expf(s[r] * 0.125f + rr[r] + mv);
      ls[r] += p;
      Pb[w][lg * 4 + r][sub * 16 + lr] = f2bf(p);
    }
  };

  kstage(0, 0);
  kstage(1, 1);   // 8 DMA outstanding

  for (int cp = 0; cp < 8; ++cp) {
    const int cA = 2 * cp;
    const int kbA = cA * 128 + w * 16;
    const int kbB = kbA + 128;

    // ---- V for BOTH sub-chunks -> 32 regs (all rows real) ----
    const float* vs = (cp < 4) ? ppv + ((n * NH + h) * SS + cA * 128) * DD
                               : pv + ((nb * NH + h) * LL + (cA - 8) * 128) * DD;
    float vraw[32];
    #pragma unroll
    for (int dt = 0; dt < 4; ++dt)
      #pragma unroll
      for (int e = 0; e < 8; ++e) {
        int kslot = lg * 8 + e;
        int j = (kslot >> 4) * 128 + w * 16 + (kslot & 15);
        vraw[dt * 8 + e] = vs[j * DD + dt * 16 + lr];
      }
    float rrA[4], rrB[4];
    #pragma unroll
    for (int r = 0; r < 4; ++r) {
      rrA[r] = relbase[(lg * 4 + r) * TOTK + kbA + lr];
      rrB[r] = relbase[(lg * 4 + r) * TOTK + kbB + lr];
    }
    float mvA = mbase[kbA + lr];
    float mvB = mbase[kbB + lr];
    // outstanding now: K_cA(4) K_cB(4) + V/rel/mask(42) = 50

    __builtin_amdgcn_sched_barrier(0);
    asm volatile("s_waitcnt vmcnt(46)" ::: "memory");   // retire K_cA only
    __builtin_amdgcn_sched_barrier(0);

    qk_sub(SB, rrA, mvA, 0);                            // buf0

    __builtin_amdgcn_sched_barrier(0);
    kstage(cA + 2, 0);                                  // refill buf0
    __builtin_amdgcn_sched_barrier(0);
    asm volatile("s_waitcnt vmcnt(46)" ::: "memory");   // retire K_cB only
    __builtin_amdgcn_sched_barrier(0);

    qk_sub(SB + 128 * 64, rrB, mvB, 1);                 // buf1

    __builtin_amdgcn_sched_barrier(0);
    if (cp < 7) kstage(cA + 3, 1);                      // refill buf1
    __builtin_amdgcn_sched_barrier(0);

    // ---- PV over full 32 keys (compiler inserts counted waits for vraw) ----
    bf16x8 pa = *(const bf16x8*)(&Pb[w][lr][lg * 8]);
    #pragma unroll
    for (int dt = 0; dt < 4; ++dt) {
      bf16x8 vb;
      #pragma unroll
      for (int e = 0; e < 8; ++e) vb[e] = (short)f2bf(vraw[dt * 8 + e]);
      ctx[dt] = __builtin_amdgcn_mfma_f32_16x16x32_bf16(pa, vb, ctx[dt], 0, 0, 0);
    }
  }

  // ---- tail: chunk 16 (keys 2048..2063), w==0 only, phantom-padded to 32 ----
  if (w == 0) {
    #pragma unroll
    for (int r = 0; r < 4; ++r) Pb[0][lg * 4 + r][16 + lr] = 0;  // re-zero phantom
    const float* vs = vws + ((nb * NH + h) * NT) * DD;
    float vraw[32];
    #pragma unroll
    for (int dt = 0; dt < 4; ++dt)
      #pragma unroll
      for (int e = 0; e < 8; ++e) {
        int kslot = lg * 8 + e;
        vraw[dt * 8 + e] = (kslot < 16) ? vs[kslot * DD + dt * 16 + lr] : 0.f;
      }
    float rrT[4];
    #pragma unroll
    for (int r = 0; r < 4; ++r)
      rrT[r] = relbase[(lg * 4 + r) * TOTK + 2048 + lr];
    float mvT = mbase[2048 + lr];

    __builtin_amdgcn_sched_barrier(0);
    asm volatile("s_waitcnt vmcnt(0)" ::: "memory");
    __builtin_amdgcn_sched_barrier(0);

    qk_sub(SB, rrT, mvT, 0);                            // chunk16 staged in buf0

    bf16x8 pa = *(const bf16x8*)(&Pb[0][lr][lg * 8]);
    #pragma unroll
    for (int dt = 0; dt < 4; ++dt) {
      bf16x8 vb;
      #pragma unroll
      for (int e = 0; e < 8; ++e) vb[e] = (short)f2bf(vraw[dt * 8 + e]);
      ctx[dt] = __builtin_amdgcn_mfma_f32_16x16x32_bf16(pa, vb, ctx[dt], 0, 0, 0);
    }
  }

  // per-row l reduce across the 16 lanes of each group
  #pragma unroll
  for (int r = 0; r < 4; ++r) {
    #pragma unroll
    for (int o = 8; o >= 1; o >>= 1) ls[r] += __shfl_xor(ls[r], o, 16);
  }

  // merge 8 waves; reuse SB (syncthreads drains all counters first)
  __syncthreads();
  float* mgc = SB;                   // [8][16][64] = 32 KB
  float* mgl = SB + NWAVE * 16 * 64; // [8][16]
  #pragma unroll
  for (int dt = 0; dt < 4; ++dt)
    #pragma unroll
    for (int r = 0; r < 4; ++r)
      mgc[(w * 16 + lg * 4 + r) * 64 + dt * 16 + lr] = ctx[dt][r];
  if (lr == 0) {
    #pragma unroll
    for (int r = 0; r < 4; ++r) mgl[w * 16 + lg * 4 + r] = ls[r];
  }
  __syncthreads();
  #pragma unroll
  for (int i = 0; i < 2; ++i) {
    int idx = i * 512 + tid;
    int t = idx >> 6, d = idx & 63;
    float num = 0.f, den = 0.f;
    #pragma unroll
    for (int ww = 0; ww < NWAVE; ++ww) {
      den += mgl[ww * 16 + t];
      num += mgc[(ww * 16 + t) * 64 + d];
    }
    out[((nb * NT + t) * NH + h) * DD + d] = num / den;
  }
}

extern "C" void kernel_launch(void* const* d_in, const int* in_sizes, int n_in,
                              void* d_out, int out_size, void* d_ws, size_t ws_size,
                              hipStream_t stream) {
  const float* hidden = (const float*)d_in[0];
  const float* mask   = (const float*)d_in[1];
  const float* rel    = (const float*)d_in[2];
  const float* ppk    = (const float*)d_in[3];
  const float* ppv    = (const float*)d_in[4];
  const float* pk     = (const float*)d_in[5];
  const float* pv     = (const float*)d_in[6];
  const float* Wq     = (const float*)d_in[7];
  const float* bq     = (const float*)d_in[8];
  const float* Wk     = (const float*)d_in[9];
  const float* bk     = (const float*)d_in[10];
  const float* Wv     = (const float*)d_in[11];
  const float* bv     = (const float*)d_in[12];
  float* out = (float*)d_out;

  unsigned short* qws = (unsigned short*)d_ws;                 // 1 MB bf16 Q
  float* kws = (float*)((char*)d_ws + (1u << 20));             // 2 MB fp32 new K
  float* vws = (float*)((char*)d_ws + 3u * (1u << 20));        // 2 MB fp32 new V

  proj_kernel<<<dim3(8, 48), 256, 0, stream>>>(hidden, Wq, bq, Wk, bk, Wv, bv,
                                               qws, kws, vws);
  attn_kernel<<<dim3(512), 512, 0, stream>>>(mask, rel, ppk, ppv, pk, pv,
                                             qws, kws, vws, out);
}

// Round 10
// 108.789 us; speedup vs baseline: 1.7953x; 1.0211x over previous
//
#include <hip/hip_runtime.h>

#define NH 16
#define NT 16
#define DD 64
#define SS 1024
#define LL 1024
#define TOTK 2064
#define EE 1024
#define NWAVE 8

typedef __attribute__((ext_vector_type(8))) short bf16x8;
typedef __attribute__((ext_vector_type(4))) float f32x4;

__device__ __forceinline__ unsigned short f2bf(float x) {
  union { float f; unsigned u; } v; v.f = x;
  unsigned r = v.u + 0x7fffu + ((v.u >> 16) & 1u);
  return (unsigned short)(r >> 16);
}

// HW packed fp32->bf16 (RNE), lo <- a, hi <- b
__device__ __forceinline__ unsigned pkbf(float a, float b) {
  unsigned r;
  asm("v_cvt_pk_bf16_f32 %0, %1, %2" : "=v"(r) : "v"(a), "v"(b));
  return r;
}
union BF8 { unsigned u[4]; bf16x8 v; };

// async global->LDS DMA, 16B/lane; LDS dest = wave-uniform base + lane*16
__device__ __forceinline__ void dma16(const void* g, void* l) {
  __builtin_amdgcn_global_load_lds(
      (const __attribute__((address_space(1))) unsigned int*)g,
      (__attribute__((address_space(3))) unsigned int*)l, 16, 0, 0);
}

// ---------------- QKV projection ----------------
__global__ __launch_bounds__(256)
void proj_kernel(const float* __restrict__ hidden,
                 const float* __restrict__ Wq, const float* __restrict__ bq,
                 const float* __restrict__ Wk, const float* __restrict__ bk,
                 const float* __restrict__ Wv, const float* __restrict__ bv,
                 unsigned short* __restrict__ qws,
                 float* __restrict__ kws, float* __restrict__ vws)
{
  __shared__ alignas(16) unsigned short As[64][72];
  __shared__ alignas(16) unsigned short Bs[64][72];
  const int mtile = blockIdx.x;
  const int ntile = blockIdx.y;
  const int mat = ntile >> 4;
  const int h = ntile & 15;
  const float* Wm = (mat == 0) ? Wq : (mat == 1 ? Wk : Wv);
  const float* bm = (mat == 0) ? bq : (mat == 1 ? bk : bv);
  const int tid = threadIdx.x;
  const int lane = tid & 63, w = tid >> 6;
  const int lr = lane & 15, lg = lane >> 4;
  const int m0 = mtile * 64;

  const f32x4 fz = {0.f, 0.f, 0.f, 0.f};
  f32x4 acc[4];
  #pragma unroll
  for (int j = 0; j < 4; ++j) acc[j] = fz;

  const int srow = tid >> 4, sc4 = tid & 15;
  float4 Ar[4], Br[4];
  #pragma unroll
  for (int it = 0; it < 4; ++it) {
    Ar[it] = *(const float4*)(hidden + (m0 + srow + it * 16) * EE + sc4 * 4);
    Br[it] = *(const float4*)(Wm + (h * 64 + srow + it * 16) * EE + sc4 * 4);
  }

  for (int k0 = 0; k0 < EE; k0 += 64) {
    __syncthreads();
    #pragma unroll
    for (int it = 0; it < 4; ++it) {
      int row = srow + it * 16;
      float4 a = Ar[it], b = Br[it];
      *(uint2*)(&As[row][sc4 * 4]) = make_uint2(pkbf(a.x, a.y), pkbf(a.z, a.w));
      *(uint2*)(&Bs[row][sc4 * 4]) = make_uint2(pkbf(b.x, b.y), pkbf(b.z, b.w));
    }
    __syncthreads();
    int kn = k0 + 64;
    if (kn < EE) {
      #pragma unroll
      for (int it = 0; it < 4; ++it) {
        Ar[it] = *(const float4*)(hidden + (m0 + srow + it * 16) * EE + kn + sc4 * 4);
        Br[it] = *(const float4*)(Wm + (h * 64 + srow + it * 16) * EE + kn + sc4 * 4);
      }
    }
    #pragma unroll
    for (int hh = 0; hh < 2; ++hh) {
      bf16x8 a = *(const bf16x8*)(&As[w * 16 + lr][hh * 32 + lg * 8]);
      #pragma unroll
      for (int dt = 0; dt < 4; ++dt) {
        bf16x8 b = *(const bf16x8*)(&Bs[dt * 16 + lr][hh * 32 + lg * 8]);
        acc[dt] = __builtin_amdgcn_mfma_f32_16x16x32_bf16(a, b, acc[dt], 0, 0, 0);
      }
    }
  }

  #pragma unroll
  for (int dt = 0; dt < 4; ++dt)
    #pragma unroll
    for (int r = 0; r < 4; ++r) {
      int Mrow = m0 + w * 16 + lg * 4 + r;
      int nb = Mrow >> 4, t = Mrow & 15;
      int d = dt * 16 + lr;
      float val = acc[dt][r] + bm[h * 64 + d];
      int oi = ((nb * NH + h) * NT + t) * DD + d;
      if (mat == 0) qws[oi] = f2bf(val);
      else if (mat == 1) kws[oi] = val;
      else vws[oi] = val;
    }
}

// ---------------- fused prefix attention: DMA K, reg V, rel prefetched 1 pair ahead ----------------
__global__ __launch_bounds__(512, 2)
void attn_kernel(const float* __restrict__ mask, const float* __restrict__ rel,
                 const float* __restrict__ ppk, const float* __restrict__ ppv,
                 const float* __restrict__ pk, const float* __restrict__ pv,
                 const unsigned short* __restrict__ qws,
                 const float* __restrict__ kws, const float* __restrict__ vws,
                 float* __restrict__ out)
{
  __shared__ __align__(16) float SB[2 * 128 * 64];           // 64 KB K dbuf
  __shared__ __align__(16) unsigned short Pb[NWAVE][16][40]; // 10 KB

  const int wg = blockIdx.x;
  const int nb = wg >> 4, h = wg & 15;
  const int n = nb >> 2;
  const int tid = threadIdx.x;
  const int lane = tid & 63, w = tid >> 6;
  const int lr = lane & 15, lg = lane >> 4;

  const unsigned short* qbase = qws + ((nb * NH + h) * NT) * DD;
  bf16x8 aq0 = *(const bf16x8*)(qbase + lr * DD + lg * 8);
  bf16x8 aq1 = *(const bf16x8*)(qbase + lr * DD + lg * 8 + 32);

  const float* relbase = rel + ((nb * NH + h) * NT) * TOTK;
  const float* mbase = mask + nb * TOTK;

  const f32x4 fz = {0.f, 0.f, 0.f, 0.f};
  f32x4 ctx[4];
  float ls[4];
  #pragma unroll
  for (int dt = 0; dt < 4; ++dt) ctx[dt] = fz;
  #pragma unroll
  for (int r = 0; r < 4; ++r) ls[r] = 0.f;

  auto kstage = [&](int c, int buf) {
    const float* ks = (c < 8)  ? ppk + ((n * NH + h) * SS + c * 128) * DD
                    : (c < 16) ? pk + ((nb * NH + h) * LL + (c - 8) * 128) * DD
                               : kws + ((nb * NH + h) * NT) * DD;
    float* Kb = SB + buf * 128 * 64;
    #pragma unroll
    for (int q = 0; q < 4; ++q) {
      int Lrow = w * 16 + q * 4 + (lane >> 4);
      int colb = (lane & 15) * 16;
      int scolb = colb ^ ((Lrow & 7) << 4);
      int srow = (c == 16) ? (Lrow & 15) : Lrow;
      dma16((const char*)ks + srow * 256 + scolb, Kb + (w * 16 + q * 4) * 64);
    }
  };

  auto qk_sub = [&](const float* Kb, const float rr[4], float mv, int sub) {
    bf16x8 kbf[2];
    #pragma unroll
    for (int hh = 0; hh < 2; ++hh) {
      int c0 = (hh * 128 + lg * 32) ^ ((lr & 7) << 4);
      int c1 = (hh * 128 + lg * 32 + 16) ^ ((lr & 7) << 4);
      float4 v0 = *(const float4*)((const char*)Kb + (w * 16 + lr) * 256 + c0);
      float4 v1 = *(const float4*)((const char*)Kb + (w * 16 + lr) * 256 + c1);
      BF8 o;
      o.u[0] = pkbf(v0.x, v0.y); o.u[1] = pkbf(v0.z, v0.w);
      o.u[2] = pkbf(v1.x, v1.y); o.u[3] = pkbf(v1.z, v1.w);
      kbf[hh] = o.v;
    }
    f32x4 s = fz;
    s = __builtin_amdgcn_mfma_f32_16x16x32_bf16(aq0, kbf[0], s, 0, 0, 0);
    s = __builtin_amdgcn_mfma_f32_16x16x32_bf16(aq1, kbf[1], s, 0, 0, 0);
    #pragma unroll
    for (int r = 0; r < 4; ++r) {
      float p = __expf(s[r] * 0.125f + rr[r] + mv);
      ls[r] += p;
      Pb[w][lg * 4 + r][sub * 16 + lr] = f2bf(p);
    }
  };

  auto rel_load = [&](int cA, float (&rA)[4], float (&rB)[4], float& mA, float& mB) {
    int kbA = cA * 128 + w * 16, kbB = kbA + 128;
    #pragma unroll
    for (int r = 0; r < 4; ++r) {
      rA[r] = relbase[(lg * 4 + r) * TOTK + kbA + lr];
      rB[r] = relbase[(lg * 4 + r) * TOTK + kbB + lr];
    }
    mA = mbase[kbA + lr];
    mB = mbase[kbB + lr];
  };

  // one pair (256 keys); rel for CURRENT pair in (rA,rB,mA,mB); prefetches next into (rAn,...)
  auto pair_iter = [&](int p, float (&rA)[4], float (&rB)[4], float& mA, float& mB,
                       float (&rAn)[4], float (&rBn)[4], float& mAn, float& mBn) {
    const int cA = 2 * p;
    // V for this pair, issued first (stays in flight until PV)
    const float* vs = (p < 4) ? ppv + ((n * NH + h) * SS + cA * 128) * DD
                              : pv + ((nb * NH + h) * LL + (cA - 8) * 128) * DD;
    float vraw[32];
    #pragma unroll
    for (int dt = 0; dt < 4; ++dt)
      #pragma unroll
      for (int e = 0; e < 8; ++e) {
        int kslot = lg * 8 + e;
        int j = (kslot >> 4) * 128 + w * 16 + (kslot & 15);
        vraw[dt * 8 + e] = vs[j * DD + dt * 16 + lr];
      }

    __builtin_amdgcn_sched_barrier(0);
    asm volatile("s_waitcnt vmcnt(46)" ::: "memory");   // retire K_cA only
    __builtin_amdgcn_sched_barrier(0);

    qk_sub(SB, rA, mA, 0);

    __builtin_amdgcn_sched_barrier(0);
    kstage(cA + 2, 0);
    __builtin_amdgcn_sched_barrier(0);
    asm volatile("s_waitcnt vmcnt(41)" ::: "memory");   // guarantee K_cB retired
    __builtin_amdgcn_sched_barrier(0);

    qk_sub(SB + 128 * 64, rB, mB, 1);

    __builtin_amdgcn_sched_barrier(0);
    if (p < 7) {
      kstage(cA + 3, 1);
      rel_load(cA + 2, rAn, rBn, mAn, mBn);             // next pair's rel/mask
    }
    __builtin_amdgcn_sched_barrier(0);

    // PV over full 32 keys (auto counted-wait drains V only; K/rel prefetch stay)
    bf16x8 pa = *(const bf16x8*)(&Pb[w][lr][lg * 8]);
    #pragma unroll
    for (int dt = 0; dt < 4; ++dt) {
      BF8 o;
      #pragma unroll
      for (int q = 0; q < 4; ++q)
        o.u[q] = pkbf(vraw[dt * 8 + q * 2], vraw[dt * 8 + q * 2 + 1]);
      ctx[dt] = __builtin_amdgcn_mfma_f32_16x16x32_bf16(pa, o.v, ctx[dt], 0, 0, 0);
    }
  };

  kstage(0, 0);
  kstage(1, 1);
  float ra0[4], rb0[4], ma0, mb0, ra1[4], rb1[4], ma1, mb1;
  rel_load(0, ra0, rb0, ma0, mb0);
  ma1 = mb1 = 0.f; ra1[0]=ra1[1]=ra1[2]=ra1[3]=0.f; rb1[0]=rb1[1]=rb1[2]=rb1[3]=0.f;

  for (int p = 0; p < 8; p += 2) {
    pair_iter(p,     ra0, rb0, ma0, mb0, ra1, rb1, ma1, mb1);
    pair_iter(p + 1, ra1, rb1, ma1, mb1, ra0, rb0, ma0, mb0);
  }

  // tail: chunk 16 (keys 2048..2063), staged in buf0 at p=7; w==0 only
  if (w == 0) {
    #pragma unroll
    for (int r = 0; r < 4; ++r) Pb[0][lg * 4 + r][16 + lr] = 0;
    const float* vs = vws + ((nb * NH + h) * NT) * DD;
    float vraw[32];
    #pragma unroll
    for (int dt = 0; dt < 4; ++dt)
      #pragma unroll
      for (int e = 0; e < 8; ++e) {
        int kslot = lg * 8 + e;
        vraw[dt * 8 + e] = (kslot < 16) ? vs[kslot * DD + dt * 16 + lr] : 0.f;
      }
    float rrT[4];
    #pragma unroll
    for (int r = 0; r < 4; ++r)
      rrT[r] = relbase[(lg * 4 + r) * TOTK + 2048 + lr];
    float mvT = mbase[2048 + lr];

    __builtin_amdgcn_sched_barrier(0);
    asm volatile("s_waitcnt vmcnt(0)" ::: "memory");
    __builtin_amdgcn_sched_barrier(0);

    qk_sub(SB, rrT, mvT, 0);

    bf16x8 pa = *(const bf16x8*)(&Pb[0][lr][lg * 8]);
    #pragma unroll
    for (int dt = 0; dt < 4; ++dt) {
      BF8 o;
      #pragma unroll
      for (int q = 0; q < 4; ++q)
        o.u[q] = pkbf(vraw[dt * 8 + q * 2], vraw[dt * 8 + q * 2 + 1]);
      ctx[dt] = __builtin_amdgcn_mfma_f32_16x16x32_bf16(pa, o.v, ctx[dt], 0, 0, 0);
    }
  }

  // per-row l reduce across the 16 lanes of each group
  #pragma unroll
  for (int r = 0; r < 4; ++r) {
    #pragma unroll
    for (int o = 8; o >= 1; o >>= 1) ls[r] += __shfl_xor(ls[r], o, 16);
  }

  // merge 8 waves; reuse SB (syncthreads drains all counters)
  __syncthreads();
  float* mgc = SB;
  float* mgl = SB + NWAVE * 16 * 64;
  #pragma unroll
  for (int dt = 0; dt < 4; ++dt)
    #pragma unroll
    for (int r = 0; r < 4; ++r)
      mgc[(w * 16 + lg * 4 + r) * 64 + dt * 16 + lr] = ctx[dt][r];
  if (lr == 0) {
    #pragma unroll
    for (int r = 0; r < 4; ++r) mgl[w * 16 + lg * 4 + r] = ls[r];
  }
  __syncthreads();
  #pragma unroll
  for (int i = 0; i < 2; ++i) {
    int idx = i * 512 + tid;
    int t = idx >> 6, d = idx & 63;
    float num = 0.f, den = 0.f;
    #pragma unroll
    for (int ww = 0; ww < NWAVE; ++ww) {
      den += mgl[ww * 16 + t];
      num += mgc[(ww * 16 + t) * 64 + d];
    }
    out[((nb * NT + t) * NH + h) * DD + d] = num / den;
  }
}

extern "C" void kernel_launch(void* const* d_in, const int* in_sizes, int n_in,
                              void* d_out, int out_size, void* d_ws, size_t ws_size,
                              hipStream_t stream) {
  const float* hidden = (const float*)d_in[0];
  const float* mask   = (const float*)d_in[1];
  const float* rel    = (const float*)d_in[2];
  const float* ppk    = (const float*)d_in[3];
  const float* ppv    = (const float*)d_in[4];
  const float* pk     = (const float*)d_in[5];
  const float* pv     = (const float*)d_in[6];
  const float* Wq     = (const float*)d_in[7];
  const float* bq     = (const float*)d_in[8];
  const float* Wk     = (const float*)d_in[9];
  const float* bk     = (const float*)d_in[10];
  const float* Wv     = (const float*)d_in[11];
  const float* bv     = (const float*)d_in[12];
  float* out = (float*)d_out;

  unsigned short* qws = (unsigned short*)d_ws;                 // 1 MB bf16 Q
  float* kws = (float*)((char*)d_ws + (1u << 20));             // 2 MB fp32 new K
  float* vws = (float*)((char*)d_ws + 3u * (1u << 20));        // 2 MB fp32 new V

  proj_kernel<<<dim3(8, 48), 256, 0, stream>>>(hidden, Wq, bq, Wk, bk, Wv, bv,
                                               qws, kws, vws);
  attn_kernel<<<dim3(512), 512, 0, stream>>>(mask, rel, ppk, ppv, pk, pv,
                                             qws, kws, vws, out);
}